// Round 2
// 105.075 us; speedup vs baseline: 1.1021x; 1.1021x over previous
//
#include <hip/hip_runtime.h>
#include <hip/hip_fp16.h>
#include <math.h>
#include <stdint.h>

// SupConLossTopK, K=8192, D=256, 64 labels, T=0.1, MAX_POS=6, NEG_K=30.
// Round 12 = round-11 resubmit (bench infra flake: "container failed twice",
// no compile/correctness signature). One defensive Bc<=0 early-out added.
//  - k_prep : unchanged (fused normalize->fp16 + bucket sort + int4 meta)
//  - k_gram : v_mfma_f32_32x32x16_f16. 64x64 tile/block, 4 waves of
//             32x32 sub-tiles, full K=256 staged once into 64KB LDS with
//             chunk-XOR swizzle (slot = chunk ^ (row&31)) so stage writes and
//             fragment ds_read_b128 are both conflict-free. Replaces the
//             VALU-dot gram whose 256 wave-uniform ds_read_b128/thread were
//             LDS-return-bandwidth-bound (~1KB writeback per b128, m134).
//             Per-thread LDS insts: 256 -> 32 reads + 16 stage writes.
//  - k_anchor: unchanged (round-9: value-only argmax, dual-chain negatives)
//  - k_final : unchanged (8192-float reduce -> mean)
// No same-address global atomics anywhere (r4 lesson). Gathered 16B streams
// amortized over coalesced per-row staging (r8 lesson).
// Harness floor inside dur_us: ~44us 0xAA poison of 256MiB ws + restore +
// 4 graph launches.
// exp(sim - rowmax) ratios == exp(sim) ratios -> no rowmax pass.

#define NEGK 30
#define MAXP 6
#define MAXBC 320   // max bucket rows (actual ~128 +-11; P(>320) ~ 1e-60)
#define GT 64       // gram tile dim (64x64 per block)

typedef _Float16 h2v __attribute__((ext_vector_type(2)));
typedef _Float16 f16x8 __attribute__((ext_vector_type(8)));
typedef float f32x16 __attribute__((ext_vector_type(16)));

__device__ __forceinline__ uint64_t mix64(uint64_t z) {
  z += 0x9E3779B97F4A7C15ULL;
  z = (z ^ (z >> 30)) * 0xBF58476D1CE4E5B9ULL;
  z = (z ^ (z >> 27)) * 0x94D049BB133111EBULL;
  return z ^ (z >> 31);
}

__device__ __forceinline__ float wave_reduce_add(float p) {
#pragma unroll
  for (int o = 32; o; o >>= 1) p += __shfl_down(p, o, 64);
  return p;  // lane 0
}

// dot of 8 packed halfs (one 16B chunk) accumulated into acc
__device__ __forceinline__ float dot8h(uint4 a, uint4 b, float acc) {
  const h2v* pa = (const h2v*)&a;
  const h2v* pb = (const h2v*)&b;
#if __has_builtin(__builtin_amdgcn_fdot2)
#pragma unroll
  for (int q = 0; q < 4; ++q) acc = __builtin_amdgcn_fdot2(pa[q], pb[q], acc, false);
#else
#pragma unroll
  for (int q = 0; q < 4; ++q)
    acc += (float)pa[q].x * (float)pb[q].x + (float)pa[q].y * (float)pb[q].y;
#endif
  return acc;
}

// ---- fused: blocks 0..K/4-1 normalize rows -> fp16; block K/4 bucket sort --
__global__ __launch_bounds__(256) void k_prep(const float* __restrict__ F,
                                              const int* __restrict__ labels, int K,
                                              __half* __restrict__ Fh,
                                              int* __restrict__ g_start,
                                              int* __restrict__ g_soff,
                                              int* __restrict__ g_bucket,
                                              int4* __restrict__ g_meta) {
  __shared__ int cnt[64], start[65], cur[64], soff_s[64];
  const int tid = threadIdx.x;

  if ((int)blockIdx.x < K / 4) {
    const int row = blockIdx.x * 4 + (tid >> 6);
    const int lane = tid & 63;
    const float4 a = ((const float4*)(F + (size_t)row * 256))[lane];
    float p = a.x * a.x + a.y * a.y + a.z * a.z + a.w * a.w;
    p = wave_reduce_add(p);
    p = __shfl(p, 0, 64);
    const float inv = 1.0f / fmaxf(sqrtf(p), 1e-12f);
    union { __half2 h[2]; uint2 u; } cv;
    cv.h[0] = __float22half2_rn(make_float2(a.x * inv, a.y * inv));
    cv.h[1] = __float22half2_rn(make_float2(a.z * inv, a.w * inv));
    ((uint2*)(Fh + (size_t)row * 256))[lane] = cv.u;
    return;
  }

  // bucket block
  if (tid < 64) cnt[tid] = 0;
  __syncthreads();
  for (int t = tid; t < K; t += 256) atomicAdd(&cnt[labels[t] & 63], 1);
  __syncthreads();
  if (tid == 0) {
    int acc = 0, sacc = 0;
    for (int l = 0; l < 64; ++l) {
      start[l] = acc;
      const int B = cnt[l];
      acc += B;
      soff_s[l] = sacc;
      const int Bc = B < MAXBC ? B : MAXBC;
      sacc += Bc * Bc;
    }
    start[64] = acc;
  }
  __syncthreads();
  if (tid < 64) { cur[tid] = start[tid]; g_soff[tid] = soff_s[tid]; }
  if (tid < 65) g_start[tid] = start[tid];
  __syncthreads();
  for (int t = tid; t < K; t += 256) {
    const int l = labels[t] & 63;
    const int p = atomicAdd(&cur[l], 1);
    g_bucket[p] = t;
    g_meta[t] = make_int4(start[l], cnt[l], p - start[l], soff_s[l]);
  }
}

// ---- per-bucket Gram (sim*10, diag=-3e38) via MFMA: 64x64 tiles ----
// 4 waves/block, each owns a 32x32 sub-tile; K=256 fully staged in LDS.
// LDS chunk swizzle: 16B slot' = slot ^ (row&31) -> stage writes (fixed row,
// chunks 0..31) and fragment reads (rows 0..31, fixed slot) both hit 32
// distinct slots => floor-rate, no extra serialization.
__global__ __launch_bounds__(256) void k_gram(const __half* __restrict__ Fh,
                                              const int* __restrict__ g_start,
                                              const int* __restrict__ g_soff,
                                              const int* __restrict__ g_bucket,
                                              float* __restrict__ g_sims) {
  __shared__ uint4 sR[64 * 32];  // 64 row-rows   x 512B = 32KB
  __shared__ uint4 sC[64 * 32];  // 64 col-rows   x 512B = 32KB

  const int b  = blockIdx.x;
  const int bs = g_start[b];
  const int B  = g_start[b + 1] - bs;
  const int Bc = B < MAXBC ? B : MAXBC;
  if (Bc <= 0) return;  // defensive (empty bucket; unreachable in practice)
  const int r0 = blockIdx.y * GT;
  const int c0 = blockIdx.z * GT;
  if (r0 >= Bc || c0 >= Bc) return;
  const int tid = threadIdx.x;

  // stage 64 row-rows + 64 col-rows (clamped gather), swizzled chunk slots.
  // 32 consecutive threads cover one row's 512B -> coalesced global reads;
  // distinct swizzled slots -> conflict-free LDS writes.
  for (int u = tid; u < 64 * 32; u += 256) {
    const int r = u >> 5, ch = u & 31;
    const int sl = ch ^ (r & 31);
    const int rr = r0 + r;
    const int gr = g_bucket[bs + (rr < Bc ? rr : Bc - 1)];
    sR[(r << 5) | sl] = ((const uint4*)(Fh + (size_t)gr * 256))[ch];
    const int cc = c0 + r;
    const int gc = g_bucket[bs + (cc < Bc ? cc : Bc - 1)];
    sC[(r << 5) | sl] = ((const uint4*)(Fh + (size_t)gc * 256))[ch];
  }
  __syncthreads();

  const int wv = tid >> 6, lane = tid & 63;
  const int wr = (wv >> 1) * 32;        // sub-tile row base (0/32)
  const int wc = (wv & 1) * 32;         // sub-tile col base (0/32)
  const int rA = wr + (lane & 31);      // block-local A row
  const int rB = wc + (lane & 31);      // block-local B row (gram column)
  const int kq = lane >> 5;             // 0/1 -> +8 halfs within 16-half K-step

  f32x16 acc;
#pragma unroll
  for (int q = 0; q < 16; ++q) acc[q] = 0.0f;

  // A frag: row = lane&31, k = (lane>>5)*8 + e (8 contiguous f16 = one b128)
  // B frag: col = lane&31, same k split. K=256 -> 16 MFMAs.
#pragma unroll
  for (int it = 0; it < 16; ++it) {
    const int slot = 2 * it + kq;
    const f16x8 a  = *(const f16x8*)&sR[(rA << 5) | (slot ^ (rA & 31))];
    const f16x8 bf = *(const f16x8*)&sC[(rB << 5) | (slot ^ (rB & 31))];
    acc = __builtin_amdgcn_mfma_f32_32x32x16_f16(a, bf, acc, 0, 0, 0);
  }

  // C/D layout (verified): col = lane&31, row = (reg&3) + 8*(reg>>2) + 4*(lane>>5)
  float* outb = g_sims + g_soff[b];
  const int ccs = c0 + wc + (lane & 31);
  const bool cok = ccs < Bc;
#pragma unroll
  for (int reg = 0; reg < 16; ++reg) {
    const int row = (reg & 3) + 8 * (reg >> 2) + 4 * (lane >> 5);
    const int rrs = r0 + wr + row;
    if (cok && rrs < Bc)
      outb[(size_t)rrs * Bc + ccs] = (rrs == ccs) ? -3.0e38f : acc[reg] * 10.0f;
  }
}

// ---- per-anchor: one wave; value-only argmax + dual-chain negatives ----
// (round-9 version — strictly leaner than round-6's)
__global__ __launch_bounds__(256) void k_anchor(
    const __half* __restrict__ Fh, const int* __restrict__ g_bucket,
    const int4* __restrict__ g_meta, const float* __restrict__ g_sims,
    float* __restrict__ g_part, int K) {
  __shared__ uint4 sA[4 * 32];        // 4 waves x 512B anchor rows
  const int wv = threadIdx.x >> 6;
  const int lane = threadIdx.x & 63;
  const int i = blockIdx.x * 4 + wv;  // K multiple of 4

  // stage anchor row into wave-private LDS (independent of meta)
  ((uint2*)sA)[wv * 64 + lane] = ((const uint2*)(Fh + (size_t)i * 256))[lane];
  const uint4* sw = sA + wv * 32;

  const int4 mt = g_meta[i];          // (bucket_start, bucket_size, loc, soff)
  const int bs = mt.x, B = mt.y;
  const int Bc = B < MAXBC ? B : MAXBC;
  int loc = mt.z;
  if (loc >= Bc) loc = 0;             // unreachable in practice
  const int n_pos = B - 1;
  const int n_neg = K - B;
  const float* simrow = g_sims + mt.w + (size_t)loc * Bc;

  // sim row -> 5 registers (Bc <= 320)
  float v[5];
#pragma unroll
  for (int rr = 0; rr < 5; ++rr) {
    const int t = lane + rr * 64;
    v[rr] = (t < Bc) ? simrow[t] : -3.4e38f;
  }

  int t6 = n_neg < MAXP ? n_neg : MAXP;
  if (t6 < 1) t6 = 1;
  int take = n_pos < t6 ? n_pos : t6;
  if (n_pos <= 0 || n_neg <= 0) take = 0;
  const int target = (take > 0) ? (n_neg < NEGK ? n_neg : NEGK) : 0;

  // ---- negatives first (kick off the gathers): dual independent chains ----
  const int s = lane & 3, g = lane >> 2;
  const int n0 = g, n1 = 16 + g;
  const uint64_t z0 = mix64(((uint64_t)(uint32_t)i << 32) | (uint32_t)n0);
  const uint64_t z1 = mix64(((uint64_t)(uint32_t)i << 32) | (uint32_t)n1);
  const unsigned int r0 = (unsigned int)(((uint64_t)(uint32_t)z0 * (uint64_t)n_neg) >> 32);
  const unsigned int r1 = (unsigned int)(((uint64_t)(uint32_t)z1 * (uint64_t)n_neg) >> 32);
  const int pos0 = (r0 < (unsigned int)bs) ? (int)r0 : (int)r0 + B;
  const int pos1 = (r1 < (unsigned int)bs) ? (int)r1 : (int)r1 + B;
  const bool pv0 = (n0 < target), pv1 = (n1 < target);
  const int j0 = pv0 ? g_bucket[pos0] : 0;
  const int j1 = pv1 ? g_bucket[pos1] : 0;
  const uint4* f0 = (const uint4*)(Fh + (size_t)j0 * 256);
  const uint4* f1 = (const uint4*)(Fh + (size_t)j1 * 256);
  float d0 = 0.0f, d1 = 0.0f;
#pragma unroll
  for (int k = 0; k < 8; ++k) {
    const uint4 aw = sw[k * 4 + s];   // LDS 4-address multicast (conflict-free)
    d0 = dot8h(f0[k * 4 + s], aw, d0);
    d1 = dot8h(f1[k * 4 + s], aw, d1);
  }
  d0 += __shfl_xor(d0, 1, 64); d0 += __shfl_xor(d0, 2, 64);
  d1 += __shfl_xor(d1, 1, 64); d1 += __shfl_xor(d1, 2, 64);
  float e = 0.0f;
  if (s == 0) {
    if (pv0) e += expf(d0 * 10.0f);
    if (pv1) e += expf(d1 * 10.0f);
  }
  const float wsum = wave_reduce_add(e);

  // ---- top-take positives: value-only max + exclude-by-equality ----
  float num = 0.0f;
  for (int r = 0; r < take; ++r) {
    float best = v[0];
#pragma unroll
    for (int c = 1; c < 5; ++c) best = fmaxf(best, v[c]);
#pragma unroll
    for (int o = 1; o < 64; o <<= 1) best = fmaxf(best, __shfl_xor(best, o, 64));
    num += expf(best);
#pragma unroll
    for (int c = 0; c < 5; ++c)
      if (v[c] == best) v[c] = -3.4e38f;
  }

  if (lane == 0) {
    float ls = 0.0f;
    if (take > 0) {
      const float denom = num + wsum;
      float ratio = denom > 0.0f ? num / denom : 0.0f;
      ratio = fmaxf(ratio, 1e-8f);
      ls = -logf(ratio);
    }
    g_part[i] = ls;                   // plain store, no atomics
  }
}

// ---- reduce 8192 per-anchor losses -> mean ----
__global__ __launch_bounds__(1024) void k_final(const float* __restrict__ g_part,
                                                float* __restrict__ out, int K) {
  __shared__ float s[16];
  float p = 0.0f;
  for (int t = threadIdx.x; t < K; t += 1024) p += g_part[t];
  p = wave_reduce_add(p);
  if ((threadIdx.x & 63) == 0) s[threadIdx.x >> 6] = p;
  __syncthreads();
  if (threadIdx.x == 0) {
    float tot = 0.0f;
#pragma unroll
    for (int w = 0; w < 16; ++w) tot += s[w];
    out[0] = tot / (float)K;
  }
}

extern "C" void kernel_launch(void* const* d_in, const int* in_sizes, int n_in,
                              void* d_out, int out_size, void* d_ws, size_t ws_size,
                              hipStream_t stream) {
  (void)n_in; (void)out_size; (void)ws_size;
  const float* F = (const float*)d_in[0];
  const int* labels = (const int*)d_in[1];
  const int K = in_sizes[1];  // 8192; D=256 hard-assumed
  float* out = (float*)d_out;

  char* ws = (char*)d_ws;
  size_t off = 0;
  int*   g_start  = (int*)(ws + off);   off += 512;
  int*   g_soff   = (int*)(ws + off);   off += 256;
  int*   g_bucket = (int*)(ws + off);   off += (size_t)K * 4;
  float* g_part   = (float*)(ws + off); off += (size_t)K * 4;
  off = (off + 255) & ~(size_t)255;
  int4*  g_meta   = (int4*)(ws + off);  off += (size_t)K * 16;
  __half* Fh      = (__half*)(ws + off); off += (size_t)K * 256 * 2;
  float* g_sims   = (float*)(ws + off);  off += (size_t)MAXBC * K * 4;

  k_prep<<<K / 4 + 1, 256, 0, stream>>>(F, labels, K, Fh, g_start, g_soff,
                                        g_bucket, g_meta);
  {
    dim3 grid(64, (MAXBC + GT - 1) / GT, (MAXBC + GT - 1) / GT);
    k_gram<<<grid, 256, 0, stream>>>(Fh, g_start, g_soff, g_bucket, g_sims);
  }
  k_anchor<<<K / 4, 256, 0, stream>>>(Fh, g_bucket, g_meta, g_sims, g_part, K);
  k_final<<<1, 1024, 0, stream>>>(g_part, out, K);
}